// Round 17
// baseline (311.495 us; speedup 1.0000x reference)
//
#include <hip/hip_runtime.h>
#include <math.h>

#define NN 20000
#define EE 640000
#define NB4C 5000
#define NCH 80          // edge chunks per graph
#define CHE 8000        // edges per chunk (NCH*CHE == EE)

typedef unsigned short ushortT;
typedef unsigned int uintT;

__device__ __forceinline__ float lrelu(float x){ return x >= 0.f ? x : 0.2f*x; }
__device__ __forceinline__ ushortT f2bf(float x){
  uintT u = __float_as_uint(x);
  u = (u + 0x7FFFu + ((u >> 16) & 1u)) >> 16;   // RNE
  return (ushortT)u;
}
__device__ __forceinline__ float bfl(uintT w){ return __uint_as_float(w << 16); }
__device__ __forceinline__ float bfh(uintT w){ return __uint_as_float(w & 0xFFFF0000u); }

// ---------------- fused: metadata GEMV+pack (P, 22048 floats)  UNION  LDS histogram
// P layout: W1@0(128) B1@128 AL1@256 AR1@384 / W2@512 B2@4608 AL2@4640 AR2@4672
// W3@4704 B3@8800 AL3@8928 AR3@9056 / W4@9184 B4@13280 AL4@13312 AR4@13344
// W5@13376 B5@17472 AL5@17600 AR5@17728 / W6@17856 B6@21952 AL6@21984 AR6@22016
__global__ __launch_bounds__(256) void k_prmhist(const float* __restrict__ m1,
        const float* __restrict__ mt, const float* __restrict__ Whin,
        const float* __restrict__ bhin, const float* __restrict__ Whout,
        const float* __restrict__ bhout, float* __restrict__ P,
        const int* __restrict__ dst_in, const int* __restrict__ dst_trg,
        int* __restrict__ histB){
  __shared__ int hist[NN/2];
  int b = blockIdx.x;
  if (b < 2*NCH){
    int g = b / NCH, c = b % NCH;
    const int* dst = g ? dst_trg : dst_in;
    for (int i=threadIdx.x; i<NN/2; i+=256) hist[i] = 0;
    __syncthreads();
    int e0 = c*CHE;
    for (int k=threadIdx.x; k<CHE; k+=256){
      int d = dst[e0+k];
      atomicAdd(&hist[d>>1], (d&1) ? 65536 : 1);
    }
    __syncthreads();
    int* outp = histB + b*(NN/2);
    for (int i=threadIdx.x; i<NN/2; i+=256) outp[i] = hist[i];
    return;
  }
  int t = (b - 2*NCH)*256 + threadIdx.x;
  if (t >= 22048) return;
  int sj; bool inA;
  if      (t < 128)  { sj = 256+t;          inA=true; }
  else if (t < 256)  { sj = 384+(t-128);    inA=true; }
  else if (t < 384)  { sj = t-256;          inA=true; }
  else if (t < 512)  { sj = 128+(t-384);    inA=true; }
  else if (t < 4608) { sj = 576+(t-512);    inA=true; }
  else if (t < 4640) { sj = 4672+(t-4608);  inA=true; }
  else if (t < 4672) { sj = 512+(t-4640);   inA=true; }
  else if (t < 4704) { sj = 544+(t-4672);   inA=true; }
  else { inA=false;
    if      (t < 8800)  { int k=t-4704, o=k>>5, i=k&31; sj = 768 + (o>>5)*3072+(o&31)*32+i; }
    else if (t < 8928)  { int o=t-8800; sj = 13056 + (o>>5)*96+(o&31); }
    else if (t < 9056)  { int q=t-8928;       sj = (q>>6)*192+(q&63); }
    else if (t < 9184)  { int q=(t-9056)+128; sj = (q>>6)*192+(q&63); }
    else if (t < 13280) { sj = 13632 + (t-9184); }
    else if (t < 13312) { sj = 25920 + (t-13280); }
    else if (t < 13344) { sj = 13440 + (t-13312); }
    else if (t < 13376) { sj = 13472 + (t-13344); }
    else if (t < 17472) { int k=t-13376, o=k>>5, i=k&31; sj = 768 + (o>>5)*3072+(32+(o&31))*32+i; }
    else if (t < 17600) { int o=t-17472; sj = 13056 + (o>>5)*96+32+(o&31); }
    else if (t < 17728) { int q=t-17600;       sj = (q>>6)*192+64+(q&63); }
    else if (t < 17856) { int q=(t-17728)+128; sj = (q>>6)*192+64+(q&63); }
    else if (t < 21952) { sj = 13632+4096+(t-17856); }
    else if (t < 21984) { sj = 25920+32+(t-21952); }
    else if (t < 22016) { sj = 13440+64+(t-21984); }
    else                { sj = 13440+96+(t-22016); }
  }
  float acc;
  if (inA){
    acc = bhin[sj];
    #pragma unroll 8
    for (int k=0;k<64;++k) acc = fmaf(m1[k], Whin[k*4704 + sj], acc);
  } else {
    acc = bhout[sj];
    #pragma unroll 8
    for (int k=0;k<64;++k) acc = fmaf(mt[k], Whout[k*26016 + sj], acc);
  }
  P[t] = acc;
}

// ---- 2-level scan of per-node totals (fold of 80 chunk planes) -> off
__global__ __launch_bounds__(1024) void k_csrA(const int* __restrict__ histB,
        int* __restrict__ exc, int* __restrict__ bsum){
  int b = blockIdx.x, t = threadIdx.x;      // 40 blocks
  int g = b/20, c2 = b%20;
  int i = c2*1024 + t;
  int tot = 0;
  if (i < NN){
    int sh = (i&1)*16;
    for (int cb=0; cb<NCH; ++cb){
      int w = histB[(g*NCH+cb)*(NN/2) + (i>>1)];
      tot += (w >> sh) & 0xFFFF;
    }
  }
  __shared__ int s[1024];
  s[t] = tot;
  __syncthreads();
  for (int d=1; d<1024; d<<=1){
    int v = (t>=d) ? s[t-d] : 0;
    __syncthreads();
    s[t] += v;
    __syncthreads();
  }
  exc[b*1024 + t] = s[t] - tot;
  if (t == 1023) bsum[b] = s[t];
}

// serial fold of 40 block sums + P2 dots + off[NN]
__global__ void k_csrB(const int* __restrict__ bsum, int* __restrict__ bbase,
        int* __restrict__ off_in, int* __restrict__ off_trg,
        const float* __restrict__ P, float* __restrict__ P2){
  int t = threadIdx.x;
  if (t < 8){
    int hh = t >> 1, sel = t & 1;
    const float* W = P;
    const float* A = P + 256 + sel*128;
    float c = 0.f;
    #pragma unroll 8
    for (int d=0; d<32; ++d) c = fmaf(W[hh*32+d], A[hh*32+d], c);
    P2[sel*4 + hh] = c;
  } else if (t == 8){
    int base = 0;
    for (int b=0; b<20; ++b){ bbase[b] = base; base += bsum[b]; }
  } else if (t == 9){
    int base = 0;
    for (int b=20; b<40; ++b){ bbase[b] = base; base += bsum[b]; }
  } else if (t == 10) off_in[NN]  = EE;
  else if   (t == 11) off_trg[NN] = EE;
}

// merged: off[i] write + per-chunk running prefix -> bases[g][chunk][node]
__global__ __launch_bounds__(1024) void k_csrC(const int* __restrict__ histB,
        const int* __restrict__ exc, const int* __restrict__ bbase,
        int* __restrict__ off_in, int* __restrict__ off_trg,
        int* __restrict__ bases){
  int b = blockIdx.x, t = threadIdx.x;      // 40 blocks
  int g = b/20, c2 = b%20;
  int i = c2*1024 + t;
  if (i >= NN) return;
  int* off = g ? off_trg : off_in;
  int running = exc[b*1024 + t] + bbase[b];
  off[i] = running;
  int sh = (i&1)*16;
  for (int cb=0; cb<NCH; ++cb){
    bases[(g*NCH+cb)*NN + i] = running;
    int w = histB[(g*NCH+cb)*(NN/2) + (i>>1)];
    running += (w >> sh) & 0xFFFF;
  }
}

// fill: block = (graph, node-half, chunk); LDS bump allocator (no global atomic returns)
__global__ __launch_bounds__(256) void k_fillL(const int* __restrict__ src_in,
        const int* __restrict__ dst_in, const int* __restrict__ src_trg,
        const int* __restrict__ dst_trg, const int* __restrict__ bases,
        ushortT* __restrict__ csr_in, ushortT* __restrict__ csr_trg){
  int b = blockIdx.x;                  // 0..319
  int g = b / (2*NCH);
  int rem = b % (2*NCH);
  int half = rem / NCH, c = rem % NCH;
  const int* src = g ? src_trg : src_in;
  const int* dst = g ? dst_trg : dst_in;
  ushortT* csr = g ? csr_trg : csr_in;
  __shared__ int alloc[NN/2];
  const int* basep = bases + (g*NCH+c)*NN + half*(NN/2);
  for (int i=threadIdx.x; i<NN/2; i+=256) alloc[i] = basep[i];
  __syncthreads();
  int e0 = c*CHE;
  int lo = half*(NN/2);
  for (int k=threadIdx.x; k<CHE; k+=256){
    int d = dst[e0+k];
    int dl = d - lo;
    if ((unsigned)dl < (unsigned)(NN/2)){
      int p = atomicAdd(&alloc[dl], 1);
      csr[p] = (ushortT)src[e0+k];
    }
  }
}

// ---------------- standalone feat+el/er (layers 4,6 input): feat bf16 [h][NN][32]
// grid-stride (stage W once per block)
template<int IN, int OUT, int H>
__global__ __launch_bounds__(256) void k_featel(const float* __restrict__ z,
        const float* __restrict__ W, const float* __restrict__ AL,
        const float* __restrict__ AR, ushortT* __restrict__ featb,
        float* __restrict__ el, float* __restrict__ er){
  __shared__ float Ws[IN*(OUT+1)];
  __shared__ float ALs[OUT], ARs[OUT];
  for (int idx=threadIdx.x; idx<IN*OUT; idx+=256){
    int o = idx / IN, i = idx % IN;
    Ws[i*(OUT+1) + o] = W[idx];
  }
  for (int idx=threadIdx.x; idx<OUT; idx+=256){ ALs[idx]=AL[idx]; ARs[idx]=AR[idx]; }
  __syncthreads();
  const int NCHK = (NN*OUT)/256;
  for (int chunk = blockIdx.x; chunk < NCHK; chunk += gridDim.x){
    int tid = chunk*256 + threadIdx.x;
    int n = tid / OUT, o = tid % OUT;
    const float4* z4 = (const float4*)(z + n*IN);
    float acc = 0.f;
    #pragma unroll
    for (int i=0;i<IN/4;++i){
      float4 zv = z4[i];
      acc = fmaf(zv.x, Ws[(4*i+0)*(OUT+1)+o], acc);
      acc = fmaf(zv.y, Ws[(4*i+1)*(OUT+1)+o], acc);
      acc = fmaf(zv.z, Ws[(4*i+2)*(OUT+1)+o], acc);
      acc = fmaf(zv.w, Ws[(4*i+3)*(OUT+1)+o], acc);
    }
    int h = o >> 5, d = o & 31;
    featb[(h*NN + n)*32 + d] = f2bf(acc);
    float a = acc * ALs[o], b = acc * ARs[o];
    #pragma unroll
    for (int msk=1; msk<32; msk<<=1){
      a += __shfl_xor(a, msk);
      b += __shfl_xor(b, msk);
    }
    if (d == 0){
      el[h*NN + n] = a;
      er[h*NN + n] = b;
    }
  }
}

// ---------------- layer 1 FUSED with featel<128,32,1> (R17): the wave holds the
// full 128-wide z row -> stage to LDS, compute layer-2 feat (bf16) + el/er directly.
// No zA write.
__global__ __launch_bounds__(256) void k_l1F(const int* __restrict__ off,
        const ushortT* __restrict__ csr, const float* __restrict__ X,
        const float* __restrict__ P, const float* __restrict__ P2,
        ushortT* __restrict__ featb, float* __restrict__ el, float* __restrict__ er){
  __shared__ float zs[4][128];
  int wv = threadIdx.x >> 6, l = threadIdx.x & 63;
  int n = blockIdx.x*4 + wv;
  if (n >= NN) return;
  int start = off[n], deg = off[n+1] - start;
  int hl = l & 3, jl = l >> 2;
  float cl = P2[hl], cr = P2[4 + hl];
  float xd = X[n];
  float m = -INFINITY, ssum = 0.f, t = 0.f;
  for (int j = jl; j < deg; j += 16){
    int s = csr[start + j];
    float xs = X[s];
    float e = lrelu(xs*cl + xd*cr);
    if (e > m){
      float w = __expf(m - e);
      ssum = ssum*w + 1.f;
      t    = t*w + xs;
      m = e;
    } else {
      float w = __expf(e - m);
      ssum += w;
      t    = fmaf(w, xs, t);
    }
  }
  #pragma unroll
  for (int msk=4; msk<64; msk<<=1){
    float mo = __shfl_xor(m, msk), so = __shfl_xor(ssum, msk), to = __shfl_xor(t, msk);
    float mn = fmaxf(m, mo);
    if (mn > -INFINITY){
      float w1 = __expf(m - mn), w2 = __expf(mo - mn);
      ssum = ssum*w1 + so*w2;
      t    = t*w1 + to*w2;
    }
    m = mn;
  }
  float tv = t / (ssum + 1e-9f);
  float th = __shfl(tv, l >> 4);
  const float2 w2v = *(const float2*)(P + 2*l);
  const float2 b2v = *(const float2*)(P + 128 + 2*l);
  zs[wv][2*l]   = fmaf(th, w2v.x, b2v.x);
  zs[wv][2*l+1] = fmaf(th, w2v.y, b2v.y);
  // fused featel<128,32,1>: 2 lanes per output, halves of the i-range
  int oo = l >> 1, half = l & 1;
  const float* Wp = P + 512 + oo*128 + half*64;
  const float* zp = zs[wv] + half*64;
  float acc = 0.f;
  #pragma unroll 8
  for (int i=0;i<64;++i) acc = fmaf(zp[i], Wp[i], acc);
  acc += __shfl_xor(acc, 1);          // both lanes of the pair hold feat_oo
  if (!half) featb[n*32 + oo] = f2bf(acc);
  float pa = half ? 0.f : acc * P[4640 + oo];
  float pb = half ? 0.f : acc * P[4672 + oo];
  #pragma unroll
  for (int msk=1; msk<64; msk<<=1){ pa += __shfl_xor(pa, msk); pb += __shfl_xor(pb, msk); }
  if (l == 0){ el[n] = pa; er[n] = pb; }
}

// ---------------- H=1 aggregation core (R13 form) + optional fused featel<32,128,4>.
// FUSE: after ELU, stage 32-wide z row to LDS; each lane computes outputs l and 64+l
// of the next layer's 128 feats (W 16KB, L1-hot), writes bf16 planes + el/er (4 heads).
// No z write when fused. All shfl/LDS loops keep wave-uniform trip counts (R5).
template<bool ELU, bool FUSE>
__global__ __launch_bounds__(256) void k_agg1(const int* __restrict__ off,
        const ushortT* __restrict__ csr, const ushortT* __restrict__ featb,
        const float* __restrict__ el, const float* __restrict__ er,
        const float* __restrict__ bias, float* __restrict__ out,
        const float* __restrict__ Wf, const float* __restrict__ ALf,
        const float* __restrict__ ARf, ushortT* __restrict__ featb2,
        float* __restrict__ el2, float* __restrict__ er2){
  __shared__ float2 as_[4][64];
  __shared__ float zr[4][32];
  int wv = threadIdx.x >> 6, l = threadIdx.x & 63;
  int n = blockIdx.x*4 + wv;
  if (n >= NN) return;
  int start = off[n], deg = off[n+1] - start;
  float erl = er[n];
  int g = l >> 3, dl = l & 7;
  float4 acc = make_float4(0.f, 0.f, 0.f, 0.f);
  float asum = 0.f;
  if (deg <= 64){
    int s = 0; float e = -INFINITY;
    if (l < deg){ s = csr[start + l]; e = lrelu(el[s] + erl); }
    float m = e;
    #pragma unroll
    for (int msk=1; msk<64; msk<<=1) m = fmaxf(m, __shfl_xor(m, msk));
    float a = (l < deg) ? __expf(e - m) : 0.f;
    as_[wv][l] = make_float2(a, __int_as_float(s));
    #pragma unroll 4
    for (int jj = 0; jj < deg; jj += 8){
      float2 pr = as_[wv][jj + g];
      float aj = pr.x; int sj = __float_as_int(pr.y);
      uint2 w = *(const uint2*)(featb + sj*32 + 4*dl);
      acc.x = fmaf(aj, bfl(w.x), acc.x);
      acc.y = fmaf(aj, bfh(w.x), acc.y);
      acc.z = fmaf(aj, bfl(w.y), acc.z);
      acc.w = fmaf(aj, bfh(w.y), acc.w);
      asum += aj;
    }
  } else {
    float m = -INFINITY;
    for (int j0 = 0; j0 < deg; j0 += 64){
      int j = j0 + l;
      int s = 0; float e = -INFINITY;
      if (j < deg){ s = csr[start + j]; e = lrelu(el[s] + erl); }
      float cm = e;
      #pragma unroll
      for (int msk=1; msk<64; msk<<=1) cm = fmaxf(cm, __shfl_xor(cm, msk));
      float mn = fmaxf(m, cm);
      float rs = __expf(m - mn);
      float a = (j < deg) ? __expf(e - mn) : 0.f;
      acc.x *= rs; acc.y *= rs; acc.z *= rs; acc.w *= rs;
      asum *= rs;
      m = mn;
      as_[wv][l] = make_float2(a, __int_as_float(s));
      int cnt = deg - j0; if (cnt > 64) cnt = 64;
      #pragma unroll 4
      for (int jj = 0; jj < cnt; jj += 8){
        float2 pr = as_[wv][jj + g];
        float aj = pr.x; int sj = __float_as_int(pr.y);
        uint2 w = *(const uint2*)(featb + sj*32 + 4*dl);
        acc.x = fmaf(aj, bfl(w.x), acc.x);
        acc.y = fmaf(aj, bfh(w.x), acc.y);
        acc.z = fmaf(aj, bfl(w.y), acc.z);
        acc.w = fmaf(aj, bfh(w.y), acc.w);
        asum += aj;
      }
    }
  }
  #pragma unroll
  for (int msk=8; msk<64; msk<<=1){
    acc.x += __shfl_xor(acc.x, msk);
    acc.y += __shfl_xor(acc.y, msk);
    acc.z += __shfl_xor(acc.z, msk);
    acc.w += __shfl_xor(acc.w, msk);
    asum  += __shfl_xor(asum,  msk);
  }
  float sinv = 1.f/(asum + 1e-9f);
  if (l < 8){
    const float4 b4 = *(const float4*)(bias + 4*l);
    float o0 = fmaf(acc.x, sinv, b4.x);
    float o1 = fmaf(acc.y, sinv, b4.y);
    float o2 = fmaf(acc.z, sinv, b4.z);
    float o3 = fmaf(acc.w, sinv, b4.w);
    if (ELU){
      o0 = o0 > 0.f ? o0 : expm1f(o0);
      o1 = o1 > 0.f ? o1 : expm1f(o1);
      o2 = o2 > 0.f ? o2 : expm1f(o2);
      o3 = o3 > 0.f ? o3 : expm1f(o3);
    }
    if (FUSE){
      zr[wv][4*l+0] = o0; zr[wv][4*l+1] = o1;
      zr[wv][4*l+2] = o2; zr[wv][4*l+3] = o3;
    } else {
      *(float4*)(out + n*32 + 4*l) = make_float4(o0, o1, o2, o3);
    }
  }
  if (FUSE){
    int o0 = l, o1 = 64 + l;
    float f0 = 0.f, f1 = 0.f;
    #pragma unroll 8
    for (int i=0;i<32;++i){
      float zi = zr[wv][i];
      f0 = fmaf(zi, Wf[o0*32+i], f0);
      f1 = fmaf(zi, Wf[o1*32+i], f1);
    }
    int h0 = l >> 5, h1 = 2 + (l >> 5), d = l & 31;
    featb2[(h0*NN + n)*32 + d] = f2bf(f0);
    featb2[(h1*NN + n)*32 + d] = f2bf(f1);
    float pa0 = f0*ALf[o0], pb0 = f0*ARf[o0];
    float pa1 = f1*ALf[o1], pb1 = f1*ARf[o1];
    #pragma unroll
    for (int msk=1; msk<32; msk<<=1){
      pa0 += __shfl_xor(pa0, msk); pb0 += __shfl_xor(pb0, msk);
      pa1 += __shfl_xor(pa1, msk); pb1 += __shfl_xor(pb1, msk);
    }
    if (d == 0){
      el2[h0*NN + n] = pa0; er2[h0*NN + n] = pb0;
      el2[h1*NN + n] = pa1; er2[h1*NN + n] = pb1;
    }
  }
}

// ---------------- H=4 aggregation (EXACT R13/R16 form — empirically best)
template<int H, bool ELU>
__global__ __launch_bounds__(256) void k_aggH(const int* __restrict__ off,
        const ushortT* __restrict__ csr, const ushortT* __restrict__ featb,
        const float* __restrict__ el, const float* __restrict__ er,
        const float* __restrict__ bias, float* __restrict__ out){
  __shared__ float2 as_[4][64];
  int wv = threadIdx.x >> 6, l = threadIdx.x & 63;
  int bid = blockIdx.x;
  int h = bid / NB4C, b = bid % NB4C;
  int n = b*4 + wv;
  if (n >= NN) return;
  const float* elh = el + h*NN;
  const ushortT* fh = featb + (size_t)h*NN*32;
  int start = off[n], deg = off[n+1] - start;
  float erl = er[h*NN + n];
  int g = l >> 3, dl = l & 7;
  float4 acc = make_float4(0.f, 0.f, 0.f, 0.f);
  float asum = 0.f;
  if (deg <= 64){
    int s = 0; float e = -INFINITY;
    if (l < deg){ s = csr[start + l]; e = lrelu(elh[s] + erl); }
    float m = e;
    #pragma unroll
    for (int msk=1; msk<64; msk<<=1) m = fmaxf(m, __shfl_xor(m, msk));
    float a = (l < deg) ? __expf(e - m) : 0.f;
    as_[wv][l] = make_float2(a, __int_as_float(s));
    #pragma unroll 4
    for (int jj = 0; jj < deg; jj += 8){
      float2 pr = as_[wv][jj + g];
      float aj = pr.x; int sj = __float_as_int(pr.y);
      uint2 w = *(const uint2*)(fh + sj*32 + 4*dl);
      acc.x = fmaf(aj, bfl(w.x), acc.x);
      acc.y = fmaf(aj, bfh(w.x), acc.y);
      acc.z = fmaf(aj, bfl(w.y), acc.z);
      acc.w = fmaf(aj, bfh(w.y), acc.w);
      asum += aj;
    }
  } else {
    float m = -INFINITY;
    for (int j0 = 0; j0 < deg; j0 += 64){
      int j = j0 + l;
      int s = 0; float e = -INFINITY;
      if (j < deg){ s = csr[start + j]; e = lrelu(elh[s] + erl); }
      float cm = e;
      #pragma unroll
      for (int msk=1; msk<64; msk<<=1) cm = fmaxf(cm, __shfl_xor(cm, msk));
      float mn = fmaxf(m, cm);
      float rs = __expf(m - mn);
      float a = (j < deg) ? __expf(e - mn) : 0.f;
      acc.x *= rs; acc.y *= rs; acc.z *= rs; acc.w *= rs;
      asum *= rs;
      m = mn;
      as_[wv][l] = make_float2(a, __int_as_float(s));
      int cnt = deg - j0; if (cnt > 64) cnt = 64;
      #pragma unroll 4
      for (int jj = 0; jj < cnt; jj += 8){
        float2 pr = as_[wv][jj + g];
        float aj = pr.x; int sj = __float_as_int(pr.y);
        uint2 w = *(const uint2*)(fh + sj*32 + 4*dl);
        acc.x = fmaf(aj, bfl(w.x), acc.x);
        acc.y = fmaf(aj, bfh(w.x), acc.y);
        acc.z = fmaf(aj, bfl(w.y), acc.z);
        acc.w = fmaf(aj, bfh(w.y), acc.w);
        asum += aj;
      }
    }
  }
  #pragma unroll
  for (int msk=8; msk<64; msk<<=1){
    acc.x += __shfl_xor(acc.x, msk);
    acc.y += __shfl_xor(acc.y, msk);
    acc.z += __shfl_xor(acc.z, msk);
    acc.w += __shfl_xor(acc.w, msk);
    asum  += __shfl_xor(asum,  msk);
  }
  float sinv = 1.f/(asum + 1e-9f);
  if (l < 8){
    const float4 b4 = *(const float4*)(bias + h*32 + 4*l);
    float o0 = fmaf(acc.x, sinv, b4.x);
    float o1 = fmaf(acc.y, sinv, b4.y);
    float o2 = fmaf(acc.z, sinv, b4.z);
    float o3 = fmaf(acc.w, sinv, b4.w);
    if (ELU){
      o0 = o0 > 0.f ? o0 : expm1f(o0);
      o1 = o1 > 0.f ? o1 : expm1f(o1);
      o2 = o2 > 0.f ? o2 : expm1f(o2);
      o3 = o3 > 0.f ? o3 : expm1f(o3);
    }
    *(float4*)(out + n*(H*32) + h*32 + 4*l) = make_float4(o0, o1, o2, o3);
  }
}

// ---------------- workspace layout (float elements) — double-buffered feat/el/er
#define WS_P     0
#define WS_P2    22144
#define WS_ELA   22272       // el A [h][NN], <=80000
#define WS_ELB   102272      // el B
#define WS_FEAT  262144      // featb A (bf16, 1.28M floats)
#define WS_FEATB 1542144     // featb B
#define WS_ZA    2822144     // f32 N x 128 (agg4 outputs)
#define WS_ZB    5382144     // now: er A / er B
#define WS_ERA   5382144
#define WS_ERB   5462144
#define WS_OFFI  6022144
#define WS_OFFT  6042240
#define WS_CSRI  6423552
#define WS_CSRT  6743552
#define WS_TOTAL 7063552     // 28.25 MB (unchanged)
// CSR-build scratch ALIASED into feat region (dead before first featb write):
#define WS_HB    (WS_FEAT + 0)        // histB: 160 * 10000 ints
#define WS_BS    (WS_FEAT + 1600000)  // bases: 160 * 20000 ints
#define WS_EXC   (WS_FEAT + 4800000)  // 40*1024 ints  (inside zA region, dead)
#define WS_BSUM  (WS_FEAT + 4841472)  // 40 ints
#define WS_BBASE (WS_FEAT + 4841600)  // 40 ints

extern "C" void kernel_launch(void* const* d_in, const int* in_sizes, int n_in,
                              void* d_out, int out_size, void* d_ws, size_t ws_size,
                              hipStream_t stream) {
  if (ws_size < (size_t)WS_TOTAL * sizeof(float)) {
    hipMemsetAsync(d_out, 0, (size_t)out_size * sizeof(float), stream);
    return;
  }
  const float* X      = (const float*)d_in[0];
  const float* m1     = (const float*)d_in[1];
  const float* mt     = (const float*)d_in[2];
  const float* Whin   = (const float*)d_in[3];
  const float* bhin   = (const float*)d_in[4];
  const float* Whout  = (const float*)d_in[5];
  const float* bhout  = (const float*)d_in[6];
  const int* src_in   = (const int*)d_in[7];
  const int* dst_in   = (const int*)d_in[8];
  const int* src_trg  = (const int*)d_in[9];
  const int* dst_trg  = (const int*)d_in[10];
  float* out = (float*)d_out;
  float* ws  = (float*)d_ws;

  float* P    = ws + WS_P;
  float* P2   = ws + WS_P2;
  float* elA  = ws + WS_ELA;
  float* elB  = ws + WS_ELB;
  float* erA  = ws + WS_ERA;
  float* erB  = ws + WS_ERB;
  ushortT* fA = (ushortT*)(ws + WS_FEAT);
  ushortT* fB = (ushortT*)(ws + WS_FEATB);
  float* zA   = ws + WS_ZA;
  int* off_in  = (int*)(ws + WS_OFFI);
  int* off_trg = (int*)(ws + WS_OFFT);
  int* histB   = (int*)(ws + WS_HB);
  int* bases   = (int*)(ws + WS_BS);
  int* exc     = (int*)(ws + WS_EXC);
  int* bsum    = (int*)(ws + WS_BSUM);
  int* bbase   = (int*)(ws + WS_BBASE);
  ushortT* csr_in  = (ushortT*)(ws + WS_CSRI);
  ushortT* csr_trg = (ushortT*)(ws + WS_CSRT);

  // params + histograms (fused, independent block ranges)
  k_prmhist<<<2*NCH + 87, 256, 0, stream>>>(m1, mt, Whin, bhin, Whout, bhout, P,
                                            dst_in, dst_trg, histB);
  k_csrA<<<40, 1024, 0, stream>>>(histB, exc, bsum);
  k_csrB<<<1, 64, 0, stream>>>(bsum, bbase, off_in, off_trg, P, P2);
  k_csrC<<<40, 1024, 0, stream>>>(histB, exc, bbase, off_in, off_trg, bases);
  k_fillL<<<4*NCH, 256, 0, stream>>>(src_in, dst_in, src_trg, dst_trg, bases,
                                     csr_in, csr_trg);

  // Layer 1 (H=4,in=1) FUSED with L2 featel -> A
  k_l1F<<<NB4C, 256, 0, stream>>>(off_in, csr_in, X, P, P2, fA, elA, erA);

  // Layer 2: agg1 (graph in) FUSED with L3 featel<32,128,4> -> B
  k_agg1<true,true><<<NB4C, 256, 0, stream>>>(off_in, csr_in, fA, elA, erA,
        P+4608, nullptr, P+4704, P+8928, P+9056, fB, elB, erB);

  // Layer 3: agg4 (graph trg) reads B -> zA
  k_aggH<4,false><<<4*NB4C, 256, 0, stream>>>(off_trg, csr_trg, fB, elB, erB,
        P+8800, zA);

  // Layer 4 featel<128,32,1> on zA -> A
  k_featel<128,32,1><<<1024, 256, 0, stream>>>(zA, P+9184, P+13312, P+13344,
        fA, elA, erA);
  // Layer 4: agg1 (trg) FUSED with L5 featel<32,128,4> -> B
  k_agg1<true,true><<<NB4C, 256, 0, stream>>>(off_trg, csr_trg, fA, elA, erA,
        P+13280, nullptr, P+13376, P+17600, P+17728, fB, elB, erB);

  // Layer 5: agg4 (trg) reads B -> zA
  k_aggH<4,false><<<4*NB4C, 256, 0, stream>>>(off_trg, csr_trg, fB, elB, erB,
        P+17472, zA);

  // Layer 6 featel<128,32,1> on zA -> A
  k_featel<128,32,1><<<1024, 256, 0, stream>>>(zA, P+17856, P+21984, P+22016,
        fA, elA, erA);
  // Layer 6: agg1 (trg) final -> out
  k_agg1<true,false><<<NB4C, 256, 0, stream>>>(off_trg, csr_trg, fA, elA, erA,
        P+21952, out, nullptr, nullptr, nullptr, nullptr, nullptr, nullptr);
}

// Round 18
// 251.398 us; speedup vs baseline: 1.2390x; 1.2390x over previous
//
#include <hip/hip_runtime.h>
#include <math.h>

#define NN 20000
#define EE 640000
#define NB4C 5000
#define NCH 80          // edge chunks per graph
#define CHE 8000        // edges per chunk (NCH*CHE == EE)

typedef unsigned short ushortT;
typedef unsigned int uintT;

__device__ __forceinline__ float lrelu(float x){ return x >= 0.f ? x : 0.2f*x; }
__device__ __forceinline__ ushortT f2bf(float x){
  uintT u = __float_as_uint(x);
  u = (u + 0x7FFFu + ((u >> 16) & 1u)) >> 16;   // RNE
  return (ushortT)u;
}
__device__ __forceinline__ float bfl(uintT w){ return __uint_as_float(w << 16); }
__device__ __forceinline__ float bfh(uintT w){ return __uint_as_float(w & 0xFFFF0000u); }

// ---------------- fused: metadata GEMV+pack (P, 22048 floats)  UNION  LDS histogram
// P layout: W1@0(128) B1@128 AL1@256 AR1@384 / W2@512 B2@4608 AL2@4640 AR2@4672
// W3@4704 B3@8800 AL3@8928 AR3@9056 / W4@9184 B4@13280 AL4@13312 AR4@13344
// W5@13376 B5@17472 AL5@17600 AR5@17728 / W6@17856 B6@21952 AL6@21984 AR6@22016
__global__ __launch_bounds__(256) void k_prmhist(const float* __restrict__ m1,
        const float* __restrict__ mt, const float* __restrict__ Whin,
        const float* __restrict__ bhin, const float* __restrict__ Whout,
        const float* __restrict__ bhout, float* __restrict__ P,
        const int* __restrict__ dst_in, const int* __restrict__ dst_trg,
        int* __restrict__ histB){
  __shared__ int hist[NN/2];
  int b = blockIdx.x;
  if (b < 2*NCH){
    int g = b / NCH, c = b % NCH;
    const int* dst = g ? dst_trg : dst_in;
    for (int i=threadIdx.x; i<NN/2; i+=256) hist[i] = 0;
    __syncthreads();
    int e0 = c*CHE;
    for (int k=threadIdx.x; k<CHE; k+=256){
      int d = dst[e0+k];
      atomicAdd(&hist[d>>1], (d&1) ? 65536 : 1);
    }
    __syncthreads();
    int* outp = histB + b*(NN/2);
    for (int i=threadIdx.x; i<NN/2; i+=256) outp[i] = hist[i];
    return;
  }
  int t = (b - 2*NCH)*256 + threadIdx.x;
  if (t >= 22048) return;
  int sj; bool inA;
  if      (t < 128)  { sj = 256+t;          inA=true; }
  else if (t < 256)  { sj = 384+(t-128);    inA=true; }
  else if (t < 384)  { sj = t-256;          inA=true; }
  else if (t < 512)  { sj = 128+(t-384);    inA=true; }
  else if (t < 4608) { sj = 576+(t-512);    inA=true; }
  else if (t < 4640) { sj = 4672+(t-4608);  inA=true; }
  else if (t < 4672) { sj = 512+(t-4640);   inA=true; }
  else if (t < 4704) { sj = 544+(t-4672);   inA=true; }
  else { inA=false;
    if      (t < 8800)  { int k=t-4704, o=k>>5, i=k&31; sj = 768 + (o>>5)*3072+(o&31)*32+i; }
    else if (t < 8928)  { int o=t-8800; sj = 13056 + (o>>5)*96+(o&31); }
    else if (t < 9056)  { int q=t-8928;       sj = (q>>6)*192+(q&63); }
    else if (t < 9184)  { int q=(t-9056)+128; sj = (q>>6)*192+(q&63); }
    else if (t < 13280) { sj = 13632 + (t-9184); }
    else if (t < 13312) { sj = 25920 + (t-13280); }
    else if (t < 13344) { sj = 13440 + (t-13312); }
    else if (t < 13376) { sj = 13472 + (t-13344); }
    else if (t < 17472) { int k=t-13376, o=k>>5, i=k&31; sj = 768 + (o>>5)*3072+(32+(o&31))*32+i; }
    else if (t < 17600) { int o=t-17472; sj = 13056 + (o>>5)*96+32+(o&31); }
    else if (t < 17728) { int q=t-17600;       sj = (q>>6)*192+64+(q&63); }
    else if (t < 17856) { int q=(t-17728)+128; sj = (q>>6)*192+64+(q&63); }
    else if (t < 21952) { sj = 13632+4096+(t-17856); }
    else if (t < 21984) { sj = 25920+32+(t-21952); }
    else if (t < 22016) { sj = 13440+64+(t-21984); }
    else                { sj = 13440+96+(t-22016); }
  }
  float acc;
  if (inA){
    acc = bhin[sj];
    #pragma unroll 8
    for (int k=0;k<64;++k) acc = fmaf(m1[k], Whin[k*4704 + sj], acc);
  } else {
    acc = bhout[sj];
    #pragma unroll 8
    for (int k=0;k<64;++k) acc = fmaf(mt[k], Whout[k*26016 + sj], acc);
  }
  P[t] = acc;
}

// ---- 2-level scan of per-node totals (fold of 80 chunk planes) -> off
__global__ __launch_bounds__(1024) void k_csrA(const int* __restrict__ histB,
        int* __restrict__ exc, int* __restrict__ bsum){
  int b = blockIdx.x, t = threadIdx.x;      // 40 blocks
  int g = b/20, c2 = b%20;
  int i = c2*1024 + t;
  int tot = 0;
  if (i < NN){
    int sh = (i&1)*16;
    for (int cb=0; cb<NCH; ++cb){
      int w = histB[(g*NCH+cb)*(NN/2) + (i>>1)];
      tot += (w >> sh) & 0xFFFF;
    }
  }
  __shared__ int s[1024];
  s[t] = tot;
  __syncthreads();
  for (int d=1; d<1024; d<<=1){
    int v = (t>=d) ? s[t-d] : 0;
    __syncthreads();
    s[t] += v;
    __syncthreads();
  }
  exc[b*1024 + t] = s[t] - tot;
  if (t == 1023) bsum[b] = s[t];
}

// merged (R18): per-block bbase from bsum (thread 0, LDS broadcast) + off[i]
// write + per-chunk running prefix -> bases. Block 0 also does P2 dots and
// off[NN]=EE (csrA->csrC dispatch ordering guarantees bsum is ready).
__global__ __launch_bounds__(1024) void k_csrC(const int* __restrict__ histB,
        const int* __restrict__ exc, const int* __restrict__ bsum,
        int* __restrict__ off_in, int* __restrict__ off_trg,
        int* __restrict__ bases, const float* __restrict__ P,
        float* __restrict__ P2){
  int b = blockIdx.x, t = threadIdx.x;      // 40 blocks
  int g = b/20, c2 = b%20;
  __shared__ int bb;
  if (t == 0){
    int s = 0;
    for (int x = g*20; x < b; ++x) s += bsum[x];
    bb = s;
  }
  if (b == 0){
    if (t >= 32 && t < 40){
      int q = t - 32;
      int hh = q >> 1, sel = q & 1;
      const float* W = P;
      const float* A = P + 256 + sel*128;
      float c = 0.f;
      #pragma unroll 8
      for (int d=0; d<32; ++d) c = fmaf(W[hh*32+d], A[hh*32+d], c);
      P2[sel*4 + hh] = c;
    } else if (t == 40) off_in[NN]  = EE;
    else if   (t == 41) off_trg[NN] = EE;
  }
  __syncthreads();
  int i = c2*1024 + t;
  if (i >= NN) return;
  int* off = g ? off_trg : off_in;
  int running = exc[b*1024 + t] + bb;
  off[i] = running;
  int sh = (i&1)*16;
  for (int cb=0; cb<NCH; ++cb){
    bases[(g*NCH+cb)*NN + i] = running;
    int w = histB[(g*NCH+cb)*(NN/2) + (i>>1)];
    running += (w >> sh) & 0xFFFF;
  }
}

// fill: block = (graph, node-half, chunk); LDS bump allocator (no global atomic returns)
__global__ __launch_bounds__(256) void k_fillL(const int* __restrict__ src_in,
        const int* __restrict__ dst_in, const int* __restrict__ src_trg,
        const int* __restrict__ dst_trg, const int* __restrict__ bases,
        ushortT* __restrict__ csr_in, ushortT* __restrict__ csr_trg){
  int b = blockIdx.x;                  // 0..319
  int g = b / (2*NCH);
  int rem = b % (2*NCH);
  int half = rem / NCH, c = rem % NCH;
  const int* src = g ? src_trg : src_in;
  const int* dst = g ? dst_trg : dst_in;
  ushortT* csr = g ? csr_trg : csr_in;
  __shared__ int alloc[NN/2];
  const int* basep = bases + (g*NCH+c)*NN + half*(NN/2);
  for (int i=threadIdx.x; i<NN/2; i+=256) alloc[i] = basep[i];
  __syncthreads();
  int e0 = c*CHE;
  int lo = half*(NN/2);
  for (int k=threadIdx.x; k<CHE; k+=256){
    int d = dst[e0+k];
    int dl = d - lo;
    if ((unsigned)dl < (unsigned)(NN/2)){
      int p = atomicAdd(&alloc[dl], 1);
      csr[p] = (ushortT)src[e0+k];
    }
  }
}

// ---------------- fused feat+el/er; feat stored BF16 TRANSPOSED [h][NN][32].
// GRID-STRIDE: stage W once per block, loop node-chunks.
template<int IN, int OUT, int H>
__global__ __launch_bounds__(256) void k_featel(const float* __restrict__ z,
        const float* __restrict__ W, const float* __restrict__ AL,
        const float* __restrict__ AR, ushortT* __restrict__ featb,
        float* __restrict__ el, float* __restrict__ er){
  __shared__ float Ws[IN*(OUT+1)];
  __shared__ float ALs[OUT], ARs[OUT];
  for (int idx=threadIdx.x; idx<IN*OUT; idx+=256){
    int o = idx / IN, i = idx % IN;
    Ws[i*(OUT+1) + o] = W[idx];
  }
  for (int idx=threadIdx.x; idx<OUT; idx+=256){ ALs[idx]=AL[idx]; ARs[idx]=AR[idx]; }
  __syncthreads();
  const int NCHK = (NN*OUT)/256;       // exact multiple
  for (int chunk = blockIdx.x; chunk < NCHK; chunk += gridDim.x){
    int tid = chunk*256 + threadIdx.x;
    int n = tid / OUT, o = tid % OUT;
    const float4* z4 = (const float4*)(z + n*IN);
    float acc = 0.f;
    #pragma unroll
    for (int i=0;i<IN/4;++i){
      float4 zv = z4[i];
      acc = fmaf(zv.x, Ws[(4*i+0)*(OUT+1)+o], acc);
      acc = fmaf(zv.y, Ws[(4*i+1)*(OUT+1)+o], acc);
      acc = fmaf(zv.z, Ws[(4*i+2)*(OUT+1)+o], acc);
      acc = fmaf(zv.w, Ws[(4*i+3)*(OUT+1)+o], acc);
    }
    int h = o >> 5, d = o & 31;
    featb[(h*NN + n)*32 + d] = f2bf(acc);
    float a = acc * ALs[o], b = acc * ARs[o];
    #pragma unroll
    for (int msk=1; msk<32; msk<<=1){
      a += __shfl_xor(a, msk);
      b += __shfl_xor(b, msk);
    }
    if (d == 0){
      el[h*NN + n] = a;
      er[h*NN + n] = b;
    }
  }
}

// ---------------- layer 1 fused (IN=1 algebraic collapse) — f32 path
__global__ __launch_bounds__(256) void k_l1(const int* __restrict__ off,
        const ushortT* __restrict__ csr, const float* __restrict__ X,
        const float* __restrict__ P, const float* __restrict__ P2,
        float* __restrict__ out){
  int wv = threadIdx.x >> 6, l = threadIdx.x & 63;
  int n = blockIdx.x*4 + wv;
  if (n >= NN) return;
  int start = off[n], deg = off[n+1] - start;
  int hl = l & 3, jl = l >> 2;
  float cl = P2[hl], cr = P2[4 + hl];
  float xd = X[n];
  float m = -INFINITY, ssum = 0.f, t = 0.f;
  for (int j = jl; j < deg; j += 16){
    int s = csr[start + j];
    float xs = X[s];
    float e = lrelu(xs*cl + xd*cr);
    if (e > m){
      float w = __expf(m - e);
      ssum = ssum*w + 1.f;
      t    = t*w + xs;
      m = e;
    } else {
      float w = __expf(e - m);
      ssum += w;
      t    = fmaf(w, xs, t);
    }
  }
  #pragma unroll
  for (int msk=4; msk<64; msk<<=1){
    float mo = __shfl_xor(m, msk), so = __shfl_xor(ssum, msk), to = __shfl_xor(t, msk);
    float mn = fmaxf(m, mo);
    if (mn > -INFINITY){
      float w1 = __expf(m - mn), w2 = __expf(mo - mn);
      ssum = ssum*w1 + so*w2;
      t    = t*w1 + to*w2;
    }
    m = mn;
  }
  float tv = t / (ssum + 1e-9f);
  float th = __shfl(tv, l >> 4);
  const float2 w2v = *(const float2*)(P + 2*l);
  const float2 b2v = *(const float2*)(P + 128 + 2*l);
  float2 o;
  o.x = fmaf(th, w2v.x, b2v.x);
  o.y = fmaf(th, w2v.y, b2v.y);
  *(float2*)(out + n*128 + 2*l) = o;
}

// ---------------- aggregation (R13/R16 form — empirically best):
// wave per (node, head), phase-major grid; bf16 feat planes [h][NN][32];
// fast path deg<=64 (plain max->exp, no rescale); (alpha,src) staged in LDS;
// PV = 8 edge-groups x 8 lanes x uint2; asum rides the group reduce.
// All shfl/LDS loops keep wave-uniform trip counts (R5 lesson).
// (R14: merged-head kills TLP. R15: 16x4xuint4 regresses. R17: epilogue
//  fusion regresses — intermediate round trips cost only ~3us here.)
template<int H, bool ELU>
__global__ __launch_bounds__(256) void k_aggH(const int* __restrict__ off,
        const ushortT* __restrict__ csr, const ushortT* __restrict__ featb,
        const float* __restrict__ el, const float* __restrict__ er,
        const float* __restrict__ bias, float* __restrict__ out){
  __shared__ float2 as_[4][64];
  int wv = threadIdx.x >> 6, l = threadIdx.x & 63;
  int bid = blockIdx.x;
  int h = bid / NB4C, b = bid % NB4C;
  int n = b*4 + wv;
  if (n >= NN) return;
  const float* elh = el + h*NN;
  const ushortT* fh = featb + (size_t)h*NN*32;
  int start = off[n], deg = off[n+1] - start;
  float erl = er[h*NN + n];
  int g = l >> 3, dl = l & 7;   // 8 edge-groups x 8 lanes; uint2 (4 bf16) per lane
  float4 acc = make_float4(0.f, 0.f, 0.f, 0.f);
  float asum = 0.f;
  if (deg <= 64){
    int s = 0; float e = -INFINITY;
    if (l < deg){ s = csr[start + l]; e = lrelu(elh[s] + erl); }
    float m = e;
    #pragma unroll
    for (int msk=1; msk<64; msk<<=1) m = fmaxf(m, __shfl_xor(m, msk));
    float a = (l < deg) ? __expf(e - m) : 0.f;
    as_[wv][l] = make_float2(a, __int_as_float(s));
    #pragma unroll 4
    for (int jj = 0; jj < deg; jj += 8){       // uniform trip count
      float2 pr = as_[wv][jj + g];             // jj+g <= 56+7 = 63
      float aj = pr.x; int sj = __float_as_int(pr.y);
      uint2 w = *(const uint2*)(fh + sj*32 + 4*dl);
      acc.x = fmaf(aj, bfl(w.x), acc.x);
      acc.y = fmaf(aj, bfh(w.x), acc.y);
      acc.z = fmaf(aj, bfl(w.y), acc.z);
      acc.w = fmaf(aj, bfh(w.y), acc.w);
      asum += aj;
    }
  } else {
    float m = -INFINITY;
    for (int j0 = 0; j0 < deg; j0 += 64){
      int j = j0 + l;
      int s = 0; float e = -INFINITY;
      if (j < deg){ s = csr[start + j]; e = lrelu(elh[s] + erl); }
      float cm = e;
      #pragma unroll
      for (int msk=1; msk<64; msk<<=1) cm = fmaxf(cm, __shfl_xor(cm, msk));
      float mn = fmaxf(m, cm);
      float rs = __expf(m - mn);     // 0 on first chunk (m=-inf), acc/asum are 0
      float a = (j < deg) ? __expf(e - mn) : 0.f;
      acc.x *= rs; acc.y *= rs; acc.z *= rs; acc.w *= rs;
      asum *= rs;
      m = mn;
      as_[wv][l] = make_float2(a, __int_as_float(s));
      int cnt = deg - j0; if (cnt > 64) cnt = 64;
      #pragma unroll 4
      for (int jj = 0; jj < cnt; jj += 8){
        float2 pr = as_[wv][jj + g];
        float aj = pr.x; int sj = __float_as_int(pr.y);
        uint2 w = *(const uint2*)(fh + sj*32 + 4*dl);
        acc.x = fmaf(aj, bfl(w.x), acc.x);
        acc.y = fmaf(aj, bfh(w.x), acc.y);
        acc.z = fmaf(aj, bfl(w.y), acc.z);
        acc.w = fmaf(aj, bfh(w.y), acc.w);
        asum += aj;
      }
    }
  }
  #pragma unroll
  for (int msk=8; msk<64; msk<<=1){
    acc.x += __shfl_xor(acc.x, msk);
    acc.y += __shfl_xor(acc.y, msk);
    acc.z += __shfl_xor(acc.z, msk);
    acc.w += __shfl_xor(acc.w, msk);
    asum  += __shfl_xor(asum,  msk);
  }
  float sinv = 1.f/(asum + 1e-9f);
  if (l < 8){
    const float4 b4 = *(const float4*)(bias + h*32 + 4*l);
    float o0 = fmaf(acc.x, sinv, b4.x);
    float o1 = fmaf(acc.y, sinv, b4.y);
    float o2 = fmaf(acc.z, sinv, b4.z);
    float o3 = fmaf(acc.w, sinv, b4.w);
    if (ELU){
      o0 = o0 > 0.f ? o0 : expm1f(o0);
      o1 = o1 > 0.f ? o1 : expm1f(o1);
      o2 = o2 > 0.f ? o2 : expm1f(o2);
      o3 = o3 > 0.f ? o3 : expm1f(o3);
    }
    *(float4*)(out + n*(H*32) + h*32 + 4*l) = make_float4(o0, o1, o2, o3);
  }
}

// ---------------- workspace layout (float elements) — ALL live buffers 512B-aligned
#define WS_P     0
#define WS_P2    22144
#define WS_EL    22272
#define WS_ER    102272
#define WS_FEAT  262144      // bf16 [h][NN][32], max 4*NN*32*2B
#define WS_ZA    2822144
#define WS_ZB    5382144
#define WS_OFFI  6022144
#define WS_OFFT  6042240
#define WS_CSRI  6423552
#define WS_CSRT  6743552
#define WS_TOTAL 7063552     // 28.25 MB (unchanged)
// CSR-build scratch ALIASED into feat+zA region (dead until k_l1 / layer 2):
#define WS_HB    (WS_FEAT + 0)        // histB: 160 * 10000 ints
#define WS_BS    (WS_FEAT + 1600000)  // bases: 160 * 20000 ints
#define WS_EXC   (WS_FEAT + 4800000)  // 40*1024 ints
#define WS_BSUM  (WS_FEAT + 4841472)  // 40 ints

extern "C" void kernel_launch(void* const* d_in, const int* in_sizes, int n_in,
                              void* d_out, int out_size, void* d_ws, size_t ws_size,
                              hipStream_t stream) {
  if (ws_size < (size_t)WS_TOTAL * sizeof(float)) {
    hipMemsetAsync(d_out, 0, (size_t)out_size * sizeof(float), stream);
    return;
  }
  const float* X      = (const float*)d_in[0];
  const float* m1     = (const float*)d_in[1];
  const float* mt     = (const float*)d_in[2];
  const float* Whin   = (const float*)d_in[3];
  const float* bhin   = (const float*)d_in[4];
  const float* Whout  = (const float*)d_in[5];
  const float* bhout  = (const float*)d_in[6];
  const int* src_in   = (const int*)d_in[7];
  const int* dst_in   = (const int*)d_in[8];
  const int* src_trg  = (const int*)d_in[9];
  const int* dst_trg  = (const int*)d_in[10];
  float* out = (float*)d_out;
  float* ws  = (float*)d_ws;

  float* P    = ws + WS_P;
  float* P2   = ws + WS_P2;
  float* el   = ws + WS_EL;
  float* er   = ws + WS_ER;
  ushortT* featb = (ushortT*)(ws + WS_FEAT);
  float* zA   = ws + WS_ZA;
  float* zB   = ws + WS_ZB;
  int* off_in  = (int*)(ws + WS_OFFI);
  int* off_trg = (int*)(ws + WS_OFFT);
  int* histB   = (int*)(ws + WS_HB);
  int* bases   = (int*)(ws + WS_BS);
  int* exc     = (int*)(ws + WS_EXC);
  int* bsum    = (int*)(ws + WS_BSUM);
  ushortT* csr_in  = (ushortT*)(ws + WS_CSRI);
  ushortT* csr_trg = (ushortT*)(ws + WS_CSRT);

  // params + histograms (fused, independent block ranges)
  k_prmhist<<<2*NCH + 87, 256, 0, stream>>>(m1, mt, Whin, bhin, Whout, bhout, P,
                                            dst_in, dst_trg, histB);
  k_csrA<<<40, 1024, 0, stream>>>(histB, exc, bsum);
  k_csrC<<<40, 1024, 0, stream>>>(histB, exc, bsum, off_in, off_trg, bases, P, P2);
  k_fillL<<<4*NCH, 256, 0, stream>>>(src_in, dst_in, src_trg, dst_trg, bases,
                                     csr_in, csr_trg);

  // Layer 1: fused (H=4, in=1) -> zA (N x 128)
  k_l1<<<NB4C, 256, 0, stream>>>(off_in, csr_in, X, P, P2, zA);

  // Layer 2: H=1, in=128 -> zB (N x 32), ELU
  k_featel<128,32,1><<<1024, 256, 0, stream>>>(zA, P+512, P+4640, P+4672, featb, el, er);
  k_aggH<1,true><<<NB4C, 256, 0, stream>>>(off_in, csr_in, featb, el, er, P+4608, zB);

  // Layer 3: H=4, in=32 -> zA (N x 128)
  k_featel<32,128,4><<<1024, 256, 0, stream>>>(zB, P+4704, P+8928, P+9056, featb, el, er);
  k_aggH<4,false><<<4*NB4C, 256, 0, stream>>>(off_trg, csr_trg, featb, el, er, P+8800, zA);

  // Layer 4: H=1, in=128 -> zB (N x 32), ELU
  k_featel<128,32,1><<<1024, 256, 0, stream>>>(zA, P+9184, P+13312, P+13344, featb, el, er);
  k_aggH<1,true><<<NB4C, 256, 0, stream>>>(off_trg, csr_trg, featb, el, er, P+13280, zB);

  // Layer 5: H=4, in=32 -> zA (N x 128)
  k_featel<32,128,4><<<1024, 256, 0, stream>>>(zB, P+13376, P+17600, P+17728, featb, el, er);
  k_aggH<4,false><<<4*NB4C, 256, 0, stream>>>(off_trg, csr_trg, featb, el, er, P+17472, zA);

  // Layer 6: H=1, in=128 -> out (N x 32), ELU
  k_featel<128,32,1><<<1024, 256, 0, stream>>>(zA, P+17856, P+21984, P+22016, featb, el, er);
  k_aggH<1,true><<<NB4C, 256, 0, stream>>>(off_trg, csr_trg, featb, el, er, P+21952, out);
}